// Round 5
// baseline (260.513 us; speedup 1.0000x reference)
//
#include <hip/hip_runtime.h>

#define NB 32
#define CCH 128
#define HH 56
#define WWD 56
#define HWP (HH*WWD)   // 3136
#define K3C (3*CCH)    // 384
#define SPLITK 8
#define LD2 200        // gemm2 LDS row stride (f16): 400B, 16B-aligned, 2-way-bank-free

typedef _Float16 half8 __attribute__((ext_vector_type(8)));
typedef _Float16 half4 __attribute__((ext_vector_type(4)));
typedef _Float16 h4u __attribute__((ext_vector_type(4), aligned(4)));
typedef float floatx4 __attribute__((ext_vector_type(4)));

// ---------------- prep: f32 -> f16 copies ----------------
__global__ __launch_bounds__(256) void cvt_kernel(const float* __restrict__ src,
                                                  _Float16* __restrict__ dst) {
    const size_t i = ((size_t)blockIdx.x * 256 + threadIdx.x) * 8;
    const float4 a = *(const float4*)(src + i);
    const float4 b = *(const float4*)(src + i + 4);
    half8 v;
    v[0] = (_Float16)a.x; v[1] = (_Float16)a.y; v[2] = (_Float16)a.z; v[3] = (_Float16)a.w;
    v[4] = (_Float16)b.x; v[5] = (_Float16)b.y; v[6] = (_Float16)b.z; v[7] = (_Float16)b.w;
    *(half8*)(dst + i) = v;
}

// ---------------- t8: t8[n,o,p] = sum_c conv_w[o,c]*p5w[c]*x[n,c,roll(p)] ----------------
// 1D grid 1568; XCD swizzle: n % 8 == bid % 8
__global__ __launch_bounds__(64) void t8_kernel(const _Float16* __restrict__ xh,
                                                const float* __restrict__ conv_w,
                                                const float* __restrict__ p5w,
                                                float* __restrict__ t8) {
    const int bid = blockIdx.x;
    const int r8  = bid & 7;
    const int g   = bid >> 3;               // 0..195
    const int n   = r8 + 8 * (g / 49);
    const int pt  = g % 49;
    const int p   = pt * 64 + threadIdx.x;
    const int proll = (p >= WWD) ? (p - WWD) : (p + (HH - 1) * WWD);
    const _Float16* xb = xh + (size_t)n * CCH * HWP + proll;
    float a0 = 0.f, a1 = 0.f, a2 = 0.f, a3 = 0.f;
#pragma unroll 4
    for (int c = 0; c < CCH; ++c) {
        const float xp = (float)xb[(size_t)c * HWP] * p5w[c];
        a0 += conv_w[c] * xp;
        a1 += conv_w[CCH + c] * xp;
        a2 += conv_w[2 * CCH + c] * xp;
        a3 += conv_w[3 * CCH + c] * xp;
    }
    float* dst = t8 + (size_t)n * 4 * HWP + p;
    dst[0] = a0; dst[HWP] = a1; dst[2 * HWP] = a2; dst[3 * HWP] = a3;
}

// ---------------- GEMM1 (split-K): part[s][n][k][c2] = sum_{p in chunk} t2[k,p]*t6[c2,p] ----
// Tm=128, Tn=128, BK=64; 1D grid 768; XCD swizzle: n % 8 == bid % 8.
__global__ __launch_bounds__(256) void gemm1_kernel(const _Float16* __restrict__ xh,
                                                    const _Float16* __restrict__ p2wh,
                                                    float* __restrict__ part) {
    __shared__ _Float16 As[128 * 72];
    __shared__ _Float16 Bs[128 * 72];

    const int bid   = blockIdx.x;
    const int r8    = bid & 7;
    const int g     = bid >> 3;             // 0..95
    const int n     = r8 + 8 * (g / 24);
    const int inner = g % 24;
    const int m0    = (inner % 3) * 128;    // k base
    const int s     = inner / 3;            // split 0..7
    const int i0    = (s * 49) >> 3;
    const int i1    = ((s + 1) * 49) >> 3;

    const int tid = threadIdx.x;
    const int r   = tid >> 1;               // 0..127
    const int c0  = (tid & 1) * 32;

    const int k   = m0 + r;
    const int ca  = k / 3;
    const int ja  = k - ca * 3;
    const int ashift = 112 * (ja - 1);
    const _Float16* xa = xh + ((size_t)n * CCH + ca) * HWP;
    const _Float16* pw = p2wh + (size_t)k * HWP;
    const _Float16* xb = xh + ((size_t)n * CCH + r) * HWP;

    const int wave = tid >> 6;
    const int lane = tid & 63;
    const int l15  = lane & 15;
    const int quad = lane >> 4;
    const int wm   = (wave >> 1) * 64;
    const int wn   = (wave & 1) * 64;

    floatx4 acc[4][4];
#pragma unroll
    for (int a = 0; a < 4; ++a)
#pragma unroll
        for (int b = 0; b < 4; ++b) acc[a][b] = (floatx4){0.f,0.f,0.f,0.f};

    for (int it = i0; it < i1; ++it) {
        const int p0 = it * 64;
#pragma unroll
        for (int seg = 0; seg < 4; ++seg) {
            const int col = c0 + seg * 8;
            const int pA  = p0 + col;
            // A
            {
                const int srcp = pA + ashift;  // 8-aligned run: wholly in/out of bounds
                half8 prod;
                if (srcp >= 0 && srcp < HWP) {
                    const half8 xv = *(const half8*)(xa + srcp);
                    const half8 wv = *(const half8*)(pw + pA);
                    prod = xv * wv;
                } else {
#pragma unroll
                    for (int i = 0; i < 8; ++i) prod[i] = (_Float16)0.f;
                }
                *(half8*)(&As[r * 72 + col]) = prod;
            }
            // B
            {
                const int proll = (pA >= WWD) ? (pA - WWD) : (pA + (HH - 1) * WWD);
                const half8 u = *(const half8*)(xb + pA);
                const half8 v = *(const half8*)(xb + proll);
                *(half8*)(&Bs[r * 72 + col]) = u + v;
            }
        }
        __syncthreads();
#pragma unroll
        for (int ks = 0; ks < 2; ++ks) {
            const int ko = ks * 32 + quad * 8;
            half8 af[4], bf[4];
#pragma unroll
            for (int mi = 0; mi < 4; ++mi) af[mi] = *(half8*)(&As[(wm + mi * 16 + l15) * 72 + ko]);
#pragma unroll
            for (int ni = 0; ni < 4; ++ni) bf[ni] = *(half8*)(&Bs[(wn + ni * 16 + l15) * 72 + ko]);
#pragma unroll
            for (int mi = 0; mi < 4; ++mi)
#pragma unroll
                for (int ni = 0; ni < 4; ++ni)
                    acc[mi][ni] = __builtin_amdgcn_mfma_f32_16x16x32_f16(af[mi], bf[ni], acc[mi][ni], 0, 0, 0);
        }
        __syncthreads();
    }

    float* pbase = part + (size_t)(s * NB + n) * K3C * CCH;
#pragma unroll
    for (int mi = 0; mi < 4; ++mi)
#pragma unroll
        for (int ni = 0; ni < 4; ++ni) {
            const int kr = m0 + wm + mi * 16 + quad * 4;
            const int cc = wn + ni * 16 + l15;
#pragma unroll
            for (int r2 = 0; r2 < 4; ++r2)
                pbase[(size_t)(kr + r2) * CCH + cc] = acc[mi][ni][r2];
        }
}

// ---------------- reduce: t7T[n][c2][k] = (1/56) * sum_s part[s][n][k][c2] ----------------
__global__ __launch_bounds__(256) void reduce_kernel(const float* __restrict__ part,
                                                     _Float16* __restrict__ t7T) {
    __shared__ _Float16 tile[16][130];
    const int n  = blockIdx.y;
    const int k0 = blockIdx.x * 16;
    const int t  = threadIdx.x;
    const int c2 = t & 127;
    const int kh = t >> 7;
#pragma unroll
    for (int kk = 0; kk < 8; ++kk) {
        const int k = kh * 8 + kk;
        float sum = 0.f;
#pragma unroll
        for (int sp = 0; sp < SPLITK; ++sp)
            sum += part[(((size_t)sp * NB + n) * K3C + k0 + k) * CCH + c2];
        tile[k][c2] = (_Float16)(sum * (1.0f / 56.0f));
    }
    __syncthreads();
    const int kt = t & 15;
    const int c0 = t >> 4;
#pragma unroll
    for (int cc = 0; cc < 8; ++cc) {
        const int cw = c0 * 8 + cc;
        t7T[((size_t)n * CCH + cw) * K3C + k0 + kt] = tile[kt][cw];
    }
}

// ---------------- GEMM2: out[n,c2,p] = t8*x + (1/sqrt(384)) sum_k t7T[c2,k]*t3[k,p] ----------
// Tm=128, Tn=64 p; BK=192, 2 K-iters (2 barrier pairs); LDS 76.8KB -> 2 blocks/CU.
// 1D grid 1568; XCD swizzle: n % 8 == bid % 8 (t7T[n] stays in one L2).
__global__ __launch_bounds__(256) void gemm2_kernel(const _Float16* __restrict__ xh,
                                                    const _Float16* __restrict__ t7T,
                                                    const float* __restrict__ t8,
                                                    float* __restrict__ out) {
    __shared__ _Float16 As[128 * LD2];   // [c2][k_local]  51.2 KB
    __shared__ _Float16 Bs[64 * LD2];    // [p][k_local]   25.6 KB

    const int bid = blockIdx.x;
    const int r8  = bid & 7;
    const int g   = bid >> 3;           // 0..195
    const int n   = r8 + 8 * (g / 49);
    const int pt0 = (g % 49) * 64;
    const int tid = threadIdx.x;

    // A staging: 2 threads per row, 12 half8 each per iter
    const int ar  = tid >> 1;           // 0..127
    const int ac0 = (tid & 1) * 96;
    const _Float16* asrc = t7T + ((size_t)n * CCH + ar) * K3C;

    // B staging: per 64-k pass: 4k x 4p per thread
    const int kb = (tid & 15) * 4;
    const int pb = (tid >> 4) * 4;
    const int pg = pt0 + pb;
    const int hB = pg / WWD;
    const int w0 = pg - hB * WWD;       // even
    const _Float16* xnh = xh + (size_t)n * CCH * HWP + hB * WWD;

    const int wave = tid >> 6;
    const int lane = tid & 63;
    const int l15  = lane & 15;
    const int quad = lane >> 4;
    const int wm   = (wave >> 1) * 64;
    const int wn   = (wave & 1) * 32;

    floatx4 acc[4][2];
#pragma unroll
    for (int a = 0; a < 4; ++a)
#pragma unroll
        for (int b = 0; b < 2; ++b) acc[a][b] = (floatx4){0.f,0.f,0.f,0.f};

#pragma unroll
    for (int k0 = 0; k0 < K3C; k0 += 192) {
        // ---- stage A: As[ar][0..191] = t7T row slice ----
#pragma unroll
        for (int seg = 0; seg < 12; ++seg)
            *(half8*)(&As[ar * LD2 + ac0 + seg * 8]) = *(const half8*)(asrc + k0 + ac0 + seg * 8);
        // ---- stage B: Bs[p][kl] = t3[k0+kl, p] = x[c, h, w + 2j - 2], zero-pad in w ----
#pragma unroll
        for (int ko2 = 0; ko2 < 192; ko2 += 64) {
            _Float16 vals[4][4];
#pragma unroll
            for (int kk = 0; kk < 4; ++kk) {
                const int k = k0 + ko2 + kb + kk;
                const int c = k / 3;
                const int j = k - c * 3;
                const int lo = w0 + 2 * j - 2;   // even
                const _Float16* row = xnh + (size_t)c * HWP;
                if (lo >= 0 && lo + 3 < WWD) {
                    const h4u v = *(const h4u*)(row + lo);
                    vals[kk][0] = v[0]; vals[kk][1] = v[1]; vals[kk][2] = v[2]; vals[kk][3] = v[3];
                } else {
#pragma unroll
                    for (int pp = 0; pp < 4; ++pp) {
                        const int w = lo + pp;
                        vals[kk][pp] = (w >= 0 && w < WWD) ? row[w] : (_Float16)0.f;
                    }
                }
            }
#pragma unroll
            for (int pp = 0; pp < 4; ++pp) {
                half4 col;
                col[0] = vals[0][pp]; col[1] = vals[1][pp];
                col[2] = vals[2][pp]; col[3] = vals[3][pp];
                *(half4*)(&Bs[(pb + pp) * LD2 + ko2 + kb]) = col;
            }
        }
        __syncthreads();
#pragma unroll
        for (int ks = 0; ks < 6; ++ks) {
            const int ko = ks * 32 + quad * 8;
            half8 af[4], bf[2];
#pragma unroll
            for (int mi = 0; mi < 4; ++mi) af[mi] = *(half8*)(&As[(wm + mi * 16 + l15) * LD2 + ko]);
#pragma unroll
            for (int ni = 0; ni < 2; ++ni) bf[ni] = *(half8*)(&Bs[(wn + ni * 16 + l15) * LD2 + ko]);
#pragma unroll
            for (int mi = 0; mi < 4; ++mi)
#pragma unroll
                for (int ni = 0; ni < 2; ++ni)
                    acc[mi][ni] = __builtin_amdgcn_mfma_f32_16x16x32_f16(af[mi], bf[ni], acc[mi][ni], 0, 0, 0);
        }
        __syncthreads();
    }

    const float sc = 0.05103103630798288f;  // 1/sqrt(384)
#pragma unroll
    for (int mi = 0; mi < 4; ++mi)
#pragma unroll
        for (int ni = 0; ni < 2; ++ni) {
            const int ccb = wm + mi * 16 + quad * 4;
            const int pp  = pt0 + wn + ni * 16 + l15;
#pragma unroll
            for (int r2 = 0; r2 < 4; ++r2) {
                const int c2 = ccb + r2;
                const size_t oidx = ((size_t)n * CCH + c2) * HWP + pp;
                const float t9 = t8[((size_t)n * 4 + (c2 & 3)) * HWP + pp] * (float)xh[oidx];
                out[oidx] = acc[mi][ni][r2] * sc + t9;
            }
        }
}

extern "C" void kernel_launch(void* const* d_in, const int* in_sizes, int n_in,
                              void* d_out, int out_size, void* d_ws, size_t ws_size,
                              hipStream_t stream) {
    const float* x      = (const float*)d_in[0];
    const float* p2w    = (const float*)d_in[1];
    const float* p5w    = (const float*)d_in[2];
    const float* conv_w = (const float*)d_in[3];
    float* out = (float*)d_out;

    // ws layout: x_h (25.69 MB) | p2w_h (2.41 MB) | t8 f32 (1.61 MB) | t7T f16 (3.15 MB)
    char* ws = (char*)d_ws;
    _Float16* xh   = (_Float16*)ws;
    _Float16* p2wh = (_Float16*)(ws + 25690112);
    float*    t8f  = (float*)   (ws + 25690112 + 2408448);
    _Float16* t7T  = (_Float16*)(ws + 25690112 + 2408448 + 1605632);
    float*    part = out;  // 12.58M f32 <= 12.85M; consumed by reduce before gemm2 writes

    cvt_kernel<<<dim3(6272), dim3(256), 0, stream>>>(x, xh);
    cvt_kernel<<<dim3(588), dim3(256), 0, stream>>>(p2w, p2wh);
    t8_kernel<<<dim3(1568), dim3(64), 0, stream>>>(xh, conv_w, p5w, t8f);
    gemm1_kernel<<<dim3(768), dim3(256), 0, stream>>>(xh, p2wh, part);
    reduce_kernel<<<dim3(24, NB), dim3(256), 0, stream>>>(part, t7T);
    gemm2_kernel<<<dim3(1568), dim3(256), 0, stream>>>(xh, t7T, t8f, out);
}

// Round 6
// 225.040 us; speedup vs baseline: 1.1576x; 1.1576x over previous
//
#include <hip/hip_runtime.h>

#define NB 32
#define CCH 128
#define HH 56
#define WWD 56
#define HWP (HH*WWD)   // 3136
#define K3C (3*CCH)    // 384
#define SPLITK 8

typedef _Float16 half8 __attribute__((ext_vector_type(8)));
typedef float floatx4 __attribute__((ext_vector_type(4)));

// ---------------- prep: x f32 -> f16 ----------------
__global__ __launch_bounds__(256) void cvt_kernel(const float* __restrict__ src,
                                                  _Float16* __restrict__ dst) {
    const size_t i = ((size_t)blockIdx.x * 256 + threadIdx.x) * 8;
    const float4 a = *(const float4*)(src + i);
    const float4 b = *(const float4*)(src + i + 4);
    half8 v;
    v[0] = (_Float16)a.x; v[1] = (_Float16)a.y; v[2] = (_Float16)a.z; v[3] = (_Float16)a.w;
    v[4] = (_Float16)b.x; v[5] = (_Float16)b.y; v[6] = (_Float16)b.z; v[7] = (_Float16)b.w;
    *(half8*)(dst + i) = v;
}

// ---------------- prep: p2w f32 -> f16, K-permuted: row k' = j*128+c <- src row (c,j) ----------
__global__ __launch_bounds__(256) void cvtp2w_kernel(const float* __restrict__ src,
                                                     _Float16* __restrict__ dst) {
    const int row = blockIdx.x;          // k' = j*128 + c
    const int j = row >> 7;
    const int c = row & 127;
    const float* s = src + ((size_t)c * 3 + j) * HWP;
    _Float16* d = dst + (size_t)row * HWP;
    for (int base = threadIdx.x * 8; base < HWP; base += 2048) {
        const float4 a = *(const float4*)(s + base);
        const float4 b = *(const float4*)(s + base + 4);
        half8 v;
        v[0] = (_Float16)a.x; v[1] = (_Float16)a.y; v[2] = (_Float16)a.z; v[3] = (_Float16)a.w;
        v[4] = (_Float16)b.x; v[5] = (_Float16)b.y; v[6] = (_Float16)b.z; v[7] = (_Float16)b.w;
        *(half8*)(d + base) = v;
    }
}

// ---------------- xT[n][p][c] = xh[n][c][p] (64x64 LDS transpose tiles) ----------------
// grid 3136 = 8 * (4n * 2c * 49p); XCD swizzle n%8 == bid%8
__global__ __launch_bounds__(256) void xt_kernel(const _Float16* __restrict__ xh,
                                                 _Float16* __restrict__ xT) {
    __shared__ _Float16 t[64 * 72];
    const int bid = blockIdx.x;
    const int r8  = bid & 7;
    const int g   = bid >> 3;            // 0..391
    const int n   = r8 + 8 * (g / 98);
    const int rem = g % 98;
    const int c0  = (rem / 49) * 64;
    const int p0  = (rem % 49) * 64;
    const int tid = threadIdx.x;
    const int r   = tid >> 2;            // 0..63
    const int seg = (tid & 3) * 16;

    const _Float16* src = xh + ((size_t)n * CCH + c0 + r) * HWP + p0 + seg;
    *(half8*)(&t[r * 72 + seg])     = *(const half8*)(src);
    *(half8*)(&t[r * 72 + seg + 8]) = *(const half8*)(src + 8);
    __syncthreads();
    // write rows of xT: p_local = r, c chunk = seg..seg+15
    _Float16* dst = xT + ((size_t)n * HWP + p0 + r) * CCH + c0 + seg;
    half8 v0, v1;
#pragma unroll
    for (int i = 0; i < 8; ++i) v0[i] = t[(seg + i) * 72 + r];
#pragma unroll
    for (int i = 0; i < 8; ++i) v1[i] = t[(seg + 8 + i) * 72 + r];
    *(half8*)(dst) = v0;
    *(half8*)(dst + 8) = v1;
}

// ---------------- t8: t8[n,o,p] = sum_c conv_w[o,c]*p5w[c]*x[n,c,roll(p)] ----------------
__global__ __launch_bounds__(64) void t8_kernel(const _Float16* __restrict__ xh,
                                                const float* __restrict__ conv_w,
                                                const float* __restrict__ p5w,
                                                float* __restrict__ t8) {
    const int bid = blockIdx.x;
    const int r8  = bid & 7;
    const int g   = bid >> 3;
    const int n   = r8 + 8 * (g / 49);
    const int p   = (g % 49) * 64 + threadIdx.x;
    const int proll = (p >= WWD) ? (p - WWD) : (p + (HH - 1) * WWD);
    const _Float16* xb = xh + (size_t)n * CCH * HWP + proll;
    float a0 = 0.f, a1 = 0.f, a2 = 0.f, a3 = 0.f;
#pragma unroll 4
    for (int c = 0; c < CCH; ++c) {
        const float xp = (float)xb[(size_t)c * HWP] * p5w[c];
        a0 += conv_w[c] * xp;
        a1 += conv_w[CCH + c] * xp;
        a2 += conv_w[2 * CCH + c] * xp;
        a3 += conv_w[3 * CCH + c] * xp;
    }
    float* dst = t8 + (size_t)n * 4 * HWP + p;
    dst[0] = a0; dst[HWP] = a1; dst[2 * HWP] = a2; dst[3 * HWP] = a3;
}

// ---------------- GEMM1 (split-K, permuted K): part[s][n][k'][c2] ----------------
// k' = j*128+c; m0-block has uniform j. Tm=128, Tn=128, BK=64; grid 768; swizzle n%8==bid%8.
__global__ __launch_bounds__(256) void gemm1_kernel(const _Float16* __restrict__ xh,
                                                    const _Float16* __restrict__ p2wh,
                                                    float* __restrict__ part) {
    __shared__ _Float16 As[128 * 72];
    __shared__ _Float16 Bs[128 * 72];

    const int bid   = blockIdx.x;
    const int r8    = bid & 7;
    const int g     = bid >> 3;
    const int n     = r8 + 8 * (g / 24);
    const int inner = g % 24;
    const int jb    = inner % 3;            // uniform j for this block
    const int m0    = jb * 128;
    const int s     = inner / 3;
    const int i0    = (s * 49) >> 3;
    const int i1    = ((s + 1) * 49) >> 3;

    const int tid = threadIdx.x;
    const int r   = tid >> 1;               // 0..127  (= c for A rows)
    const int c0  = (tid & 1) * 32;

    const int ashift = 112 * (jb - 1);
    const _Float16* xa = xh + ((size_t)n * CCH + r) * HWP;
    const _Float16* pw = p2wh + (size_t)(m0 + r) * HWP;
    const _Float16* xb = xh + ((size_t)n * CCH + r) * HWP;

    const int wave = tid >> 6;
    const int lane = tid & 63;
    const int l15  = lane & 15;
    const int quad = lane >> 4;
    const int wm   = (wave >> 1) * 64;
    const int wn   = (wave & 1) * 64;

    floatx4 acc[4][4];
#pragma unroll
    for (int a = 0; a < 4; ++a)
#pragma unroll
        for (int b = 0; b < 4; ++b) acc[a][b] = (floatx4){0.f,0.f,0.f,0.f};

    for (int it = i0; it < i1; ++it) {
        const int p0 = it * 64;
#pragma unroll
        for (int seg = 0; seg < 4; ++seg) {
            const int col = c0 + seg * 8;
            const int pA  = p0 + col;
            // A: t2'[m0+r, p] = p2w'[m0+r, p] * x[r, p+ashift]
            {
                const int srcp = pA + ashift;  // 8-aligned run: wholly in/out
                half8 prod;
                if (srcp >= 0 && srcp < HWP) {
                    const half8 xv = *(const half8*)(xa + srcp);
                    const half8 wv = *(const half8*)(pw + pA);
                    prod = xv * wv;
                } else {
#pragma unroll
                    for (int i = 0; i < 8; ++i) prod[i] = (_Float16)0.f;
                }
                *(half8*)(&As[r * 72 + col]) = prod;
            }
            // B: t6[r,p] = x[r,p] + x[r,roll(p)]
            {
                const int proll = (pA >= WWD) ? (pA - WWD) : (pA + (HH - 1) * WWD);
                const half8 u = *(const half8*)(xb + pA);
                const half8 v = *(const half8*)(xb + proll);
                *(half8*)(&Bs[r * 72 + col]) = u + v;
            }
        }
        __syncthreads();
#pragma unroll
        for (int ks = 0; ks < 2; ++ks) {
            const int ko = ks * 32 + quad * 8;
            half8 af[4], bf[4];
#pragma unroll
            for (int mi = 0; mi < 4; ++mi) af[mi] = *(half8*)(&As[(wm + mi * 16 + l15) * 72 + ko]);
#pragma unroll
            for (int ni = 0; ni < 4; ++ni) bf[ni] = *(half8*)(&Bs[(wn + ni * 16 + l15) * 72 + ko]);
#pragma unroll
            for (int mi = 0; mi < 4; ++mi)
#pragma unroll
                for (int ni = 0; ni < 4; ++ni)
                    acc[mi][ni] = __builtin_amdgcn_mfma_f32_16x16x32_f16(af[mi], bf[ni], acc[mi][ni], 0, 0, 0);
        }
        __syncthreads();
    }

    float* pbase = part + (size_t)(s * NB + n) * K3C * CCH;
#pragma unroll
    for (int mi = 0; mi < 4; ++mi)
#pragma unroll
        for (int ni = 0; ni < 4; ++ni) {
            const int kr = m0 + wm + mi * 16 + quad * 4;
            const int cc = wn + ni * 16 + l15;
#pragma unroll
            for (int r2 = 0; r2 < 4; ++r2)
                pbase[(size_t)(kr + r2) * CCH + cc] = acc[mi][ni][r2];
        }
}

// ---------------- reduce: t7T[n][c2][k'] = (1/56) * sum_s part[s][n][k'][c2] ----------------
__global__ __launch_bounds__(256) void reduce_kernel(const float* __restrict__ part,
                                                     _Float16* __restrict__ t7T) {
    __shared__ _Float16 tile[16][130];
    const int n  = blockIdx.y;
    const int k0 = blockIdx.x * 16;
    const int t  = threadIdx.x;
    const int c2 = t & 127;
    const int kh = t >> 7;
#pragma unroll
    for (int kk = 0; kk < 8; ++kk) {
        const int k = kh * 8 + kk;
        float sum = 0.f;
#pragma unroll
        for (int sp = 0; sp < SPLITK; ++sp)
            sum += part[(((size_t)sp * NB + n) * K3C + k0 + k) * CCH + c2];
        tile[k][c2] = (_Float16)(sum * (1.0f / 56.0f));
    }
    __syncthreads();
    const int kt = t & 15;
    const int c0 = t >> 4;
#pragma unroll
    for (int cc = 0; cc < 8; ++cc) {
        const int cw = c0 * 8 + cc;
        t7T[((size_t)n * CCH + cw) * K3C + k0 + kt] = tile[kt][cw];
    }
}

// ---------------- GEMM2 (permuted K): out[n,c2,p] = t8*x + sc * sum_k' t7T[c2,k']*t3'[k',p] ---
// t3'[j*128+c, p] = xT[p_shift(j)][c]; B staging = contiguous 2x16B loads. BK=64, 6 iters.
__global__ __launch_bounds__(256) void gemm2_kernel(const _Float16* __restrict__ xh,
                                                    const _Float16* __restrict__ xT,
                                                    const _Float16* __restrict__ t7T,
                                                    const float* __restrict__ t8,
                                                    float* __restrict__ out) {
    __shared__ _Float16 As[128 * 72];   // [c2][k_local]
    __shared__ _Float16 Bs[64 * 72];    // [p][k_local]

    const int bid = blockIdx.x;
    const int r8  = bid & 7;
    const int g   = bid >> 3;
    const int n   = r8 + 8 * (g / 49);
    const int pt0 = (g % 49) * 64;
    const int tid = threadIdx.x;

    // A staging: 2 threads/row, 4 half8 per iter
    const int ar = tid >> 1;
    const int ac = (tid & 1) * 32;
    const _Float16* asrc = t7T + ((size_t)n * CCH + ar) * K3C;

    // B staging: row rb (p_local), 16 f16 seg
    const int rb   = tid >> 2;          // 0..63
    const int bseg = (tid & 3) * 16;
    const int pB   = pt0 + rb;
    const int hb   = pB / WWD;
    const int wb   = pB - hb * WWD;
    const _Float16* xTn = xT + (size_t)n * HWP * CCH;

    const int wave = tid >> 6;
    const int lane = tid & 63;
    const int l15  = lane & 15;
    const int quad = lane >> 4;
    const int wm   = (wave >> 1) * 64;
    const int wn   = (wave & 1) * 32;

    floatx4 acc[4][2];
#pragma unroll
    for (int a = 0; a < 4; ++a)
#pragma unroll
        for (int b = 0; b < 2; ++b) acc[a][b] = (floatx4){0.f,0.f,0.f,0.f};

#pragma unroll
    for (int k0 = 0; k0 < K3C; k0 += 64) {
        const int j   = k0 >> 7;        // 0,0,1,1,2,2 (uniform)
        const int c0k = k0 & 127;       // 0,64,...
        // ---- stage A ----
#pragma unroll
        for (int seg = 0; seg < 4; ++seg)
            *(half8*)(&As[ar * 72 + ac + seg * 8]) = *(const half8*)(asrc + k0 + ac + seg * 8);
        // ---- stage B: Bs[rb][kl] = xT[h, wb+2j-2][c0k+kl] (row-uniform zero pad) ----
        {
            const int wsrc = wb + 2 * j - 2;
            half8 b0, b1;
            if (wsrc >= 0 && wsrc < WWD) {
                const _Float16* srcB = xTn + ((size_t)hb * WWD + wsrc) * CCH + c0k + bseg;
                b0 = *(const half8*)(srcB);
                b1 = *(const half8*)(srcB + 8);
            } else {
#pragma unroll
                for (int i = 0; i < 8; ++i) { b0[i] = (_Float16)0.f; b1[i] = (_Float16)0.f; }
            }
            *(half8*)(&Bs[rb * 72 + bseg])     = b0;
            *(half8*)(&Bs[rb * 72 + bseg + 8]) = b1;
        }
        __syncthreads();
#pragma unroll
        for (int ks = 0; ks < 2; ++ks) {
            const int ko = ks * 32 + quad * 8;
            half8 af[4], bf[2];
#pragma unroll
            for (int mi = 0; mi < 4; ++mi) af[mi] = *(half8*)(&As[(wm + mi * 16 + l15) * 72 + ko]);
#pragma unroll
            for (int ni = 0; ni < 2; ++ni) bf[ni] = *(half8*)(&Bs[(wn + ni * 16 + l15) * 72 + ko]);
#pragma unroll
            for (int mi = 0; mi < 4; ++mi)
#pragma unroll
                for (int ni = 0; ni < 2; ++ni)
                    acc[mi][ni] = __builtin_amdgcn_mfma_f32_16x16x32_f16(af[mi], bf[ni], acc[mi][ni], 0, 0, 0);
        }
        __syncthreads();
    }

    const float sc = 0.05103103630798288f;  // 1/sqrt(384)
#pragma unroll
    for (int mi = 0; mi < 4; ++mi)
#pragma unroll
        for (int ni = 0; ni < 2; ++ni) {
            const int ccb = wm + mi * 16 + quad * 4;
            const int pp  = pt0 + wn + ni * 16 + l15;
#pragma unroll
            for (int r2 = 0; r2 < 4; ++r2) {
                const int c2 = ccb + r2;
                const size_t oidx = ((size_t)n * CCH + c2) * HWP + pp;
                const float t9 = t8[((size_t)n * 4 + (c2 & 3)) * HWP + pp] * (float)xh[oidx];
                out[oidx] = acc[mi][ni][r2] * sc + t9;
            }
        }
}

extern "C" void kernel_launch(void* const* d_in, const int* in_sizes, int n_in,
                              void* d_out, int out_size, void* d_ws, size_t ws_size,
                              hipStream_t stream) {
    const float* x      = (const float*)d_in[0];
    const float* p2w    = (const float*)d_in[1];
    const float* p5w    = (const float*)d_in[2];
    const float* conv_w = (const float*)d_in[3];
    float* out = (float*)d_out;

    // ws: xh 25.69MB | p2wh 2.41MB | t8 1.61MB | t7T 3.15MB | xT 25.69MB
    char* ws = (char*)d_ws;
    _Float16* xh   = (_Float16*)ws;
    _Float16* p2wh = (_Float16*)(ws + 25690112);
    float*    t8f  = (float*)   (ws + 25690112 + 2408448);
    _Float16* t7T  = (_Float16*)(ws + 25690112 + 2408448 + 1605632);
    _Float16* xT   = (_Float16*)(ws + 25690112 + 2408448 + 1605632 + 3145728);
    float*    part = out;  // consumed by reduce before gemm2 writes out

    cvt_kernel<<<dim3(6272), dim3(256), 0, stream>>>(x, xh);
    cvtp2w_kernel<<<dim3(K3C), dim3(256), 0, stream>>>(p2w, p2wh);
    xt_kernel<<<dim3(3136), dim3(256), 0, stream>>>(xh, xT);
    t8_kernel<<<dim3(1568), dim3(64), 0, stream>>>(xh, conv_w, p5w, t8f);
    gemm1_kernel<<<dim3(768), dim3(256), 0, stream>>>(xh, p2wh, part);
    reduce_kernel<<<dim3(24, NB), dim3(256), 0, stream>>>(part, t7T);
    gemm2_kernel<<<dim3(1568), dim3(256), 0, stream>>>(xh, xT, t7T, t8f, out);
}